// Round 6
// baseline (107.977 us; speedup 1.0000x reference)
//
#include <hip/hip_runtime.h>
#include <math.h>

// Problem constants (from reference): B=2, L=1024, D=256, P=32
#define B_ 2
#define L_ 1024
#define D_ 256
#define P_ 32
#define NROW (B_*L_)          // 2048 flattened (b,l) rows
#define C_ 16                 // L chunks for the scan
#define CL_ (L_/C_)           // 64 positions per chunk
#define PIF 3.14159265358979323846f

// Native clang vector types — required by __builtin_nontemporal_store
typedef float nvf4 __attribute__((ext_vector_type(4)));
typedef float nvf2 __attribute__((ext_vector_type(2)));

// ---------------------------------------------------------------------------
// Budget model (round-5 calibrated): per-iteration fixed harness cost ~69 us
// (46 us out-fill + ~23 us ws-fill, both below top-5 cutoff). Our budget:
// proj ~12-14, partial ~6-8, scan ~12-13 (AT write roofline), gaps ~4.
// Round-6: value-reuse partial (64MB->2MB L2 reads) + phasorT LDS transpose.
// ---------------------------------------------------------------------------

// ---------------------------------------------------------------------------
// Projection kernel, 1280 blocks x 256 threads.
//  blocks [0, 1024): values GEMM, 2 rows/block, K-SPLIT: quarter-wave q owns
//    k in [64q, 64q+64); partials reduced through 8 KB LDS.
//  blocks [1024, 1280): phase GEMM, 8 rows x 32 p; fast tanh via __expf and
//    __sincosf; phases -> out, phasors -> out, transposed phasor copy via
//    LDS transpose (round-6: was 256 scattered 4-B stores/block; now one
//    wave does 32-B runs per p — 8x fewer store txns):
//      mode 1: phasorT is float  cos-only  [bp*L + l]   (256 KB)
//      mode 0: phasorT is float2 (cos,sin) [bp*L + l]   (512 KB)
// phasorMode: 0 = float2 (cos,sin), 1 = cos only, 2 = skip. hasPT: write pT.
// NO inter-block sync anywhere — round-2 lesson: agent-scope acquire/release
// storms the non-coherent per-XCD L2s (239 us). Round-4 lesson: keep work
// UNIFORM per block (triangular tail cost 50+ us).
// ---------------------------------------------------------------------------
__global__ __launch_bounds__(256) void k_proj3(
    const float* __restrict__ x, const float* __restrict__ Wp,
    const float* __restrict__ bp, const float* __restrict__ Wv,
    const float* __restrict__ bv, float* __restrict__ values,
    float* __restrict__ phases_out, float* __restrict__ phasor_out,
    float* __restrict__ phasorT, int phasorMode, int mode, int hasPT)
{
    __shared__ float smem[3072];                 // 12 KB carved below
    const int tid = threadIdx.x;

    if (blockIdx.x < NROW / 2) {
        // ---- values: rows [row0, row0+2), K-split ----
        const int row0 = blockIdx.x * 2;
        float*  xsv = smem;                      // 512 floats (2 KB)
        float4* red = (float4*)(smem + 512);     // 512 float4 (8 KB)

        if (tid < 128)
            ((float4*)xsv)[tid] = ((const float4*)(x + (size_t)row0 * D_))[tid];
        __syncthreads();

        const int q  = tid >> 6;                 // k-quarter, wave-uniform
        const int c4 = tid & 63;                 // float4 column group
        const float4* Wv4 = (const float4*)Wv;
        float4 acc0 = make_float4(0.f, 0.f, 0.f, 0.f);
        float4 acc1 = make_float4(0.f, 0.f, 0.f, 0.f);

        const int k0 = q * 64;
        for (int kk = 0; kk < 64; kk += 4) {
            const int k = k0 + kk;
            float4 w0 = Wv4[(k + 0) * 64 + c4]; // coalesced 1KB/wave
            float4 w1 = Wv4[(k + 1) * 64 + c4];
            float4 w2 = Wv4[(k + 2) * 64 + c4];
            float4 w3 = Wv4[(k + 3) * 64 + c4];
            float4 xa = *(const float4*)(xsv + 0 * D_ + k);  // bcast b128
            float4 xb = *(const float4*)(xsv + 1 * D_ + k);
            acc0.x += xa.x*w0.x + xa.y*w1.x + xa.z*w2.x + xa.w*w3.x;
            acc0.y += xa.x*w0.y + xa.y*w1.y + xa.z*w2.y + xa.w*w3.y;
            acc0.z += xa.x*w0.z + xa.y*w1.z + xa.z*w2.z + xa.w*w3.z;
            acc0.w += xa.x*w0.w + xa.y*w1.w + xa.z*w2.w + xa.w*w3.w;
            acc1.x += xb.x*w0.x + xb.y*w1.x + xb.z*w2.x + xb.w*w3.x;
            acc1.y += xb.x*w0.y + xb.y*w1.y + xb.z*w2.y + xb.w*w3.y;
            acc1.z += xb.x*w0.z + xb.y*w1.z + xb.z*w2.z + xb.w*w3.z;
            acc1.w += xb.x*w0.w + xb.y*w1.w + xb.z*w2.w + xb.w*w3.w;
        }
        red[(0 * 4 + q) * 64 + c4] = acc0;
        red[(1 * 4 + q) * 64 + c4] = acc1;
        __syncthreads();

        if (tid < 128) {
            const int r2 = tid >> 6;             // row this thread finalizes
            const int cb = tid & 63;
            float4 s0 = red[(r2 * 4 + 0) * 64 + cb];
            float4 s1 = red[(r2 * 4 + 1) * 64 + cb];
            float4 s2 = red[(r2 * 4 + 2) * 64 + cb];
            float4 s3 = red[(r2 * 4 + 3) * 64 + cb];
            const float4 b4 = ((const float4*)bv)[cb];
            float4 o;
            o.x = s0.x + s1.x + s2.x + s3.x + b4.x;
            o.y = s0.y + s1.y + s2.y + s3.y + b4.y;
            o.z = s0.z + s1.z + s2.z + s3.z + b4.z;
            o.w = s0.w + s1.w + s2.w + s3.w + b4.w;
            ((float4*)values)[(size_t)(row0 + r2) * 64 + cb] = o;
        }
    } else {
        // ---- phases/phasors: rows [row0, row0+8) ----
        const int row0 = (blockIdx.x - NROW / 2) * 8;
        float* xs = smem;                        // 2048 floats (8 KB)
        const float4* xg4 = (const float4*)(x + (size_t)row0 * D_);
        ((float4*)xs)[tid]       = xg4[tid];
        ((float4*)xs)[tid + 256] = xg4[tid + 256];
        __syncthreads();

        const int p  = tid & (P_ - 1);
        const int rr = tid >> 5;                 // 0..7
        const float* xr = xs + rr * D_;
        float a0 = 0.f, a1 = 0.f, a2 = 0.f, a3 = 0.f;
        for (int k = 0; k < D_; k += 8) {
            float w0 = Wp[(k + 0) * P_ + p];
            float w1 = Wp[(k + 1) * P_ + p];
            float w2 = Wp[(k + 2) * P_ + p];
            float w3 = Wp[(k + 3) * P_ + p];
            float w4 = Wp[(k + 4) * P_ + p];
            float w5 = Wp[(k + 5) * P_ + p];
            float w6 = Wp[(k + 6) * P_ + p];
            float w7 = Wp[(k + 7) * P_ + p];
            float4 xA = *(const float4*)(xr + k);
            float4 xB = *(const float4*)(xr + k + 4);
            a0 += xA.x * w0; a1 += xA.y * w1; a2 += xA.z * w2; a3 += xA.w * w3;
            a0 += xB.x * w4; a1 += xB.y * w5; a2 += xB.z * w6; a3 += xB.w * w7;
        }
        float a = (a0 + a1) + (a2 + a3) + bp[p];
        // fast tanh: 1 - 2/(e^{2a}+1); inf-safe at both extremes
        float e  = __expf(2.0f * a);
        float ph = (1.0f - __fdividef(2.0f, e + 1.0f)) * PIF;
        const int row = row0 + rr;
        const int idx = row * P_ + p;
        phases_out[idx] = ph;
        float s, c;
        __sincosf(ph, &s, &c);
        if (phasorMode == 0) {
            ((float2*)phasor_out)[idx] = make_float2(c, s);
        } else if (phasorMode == 1) {
            phasor_out[idx] = c;
        }
        // ---- phasorT via LDS transpose (coalesced 32/64-B runs per p) ----
        if (hasPT) {
            const int bq    = row0 >> 10;        // block never crosses b
            const int row0l = row0 & (L_ - 1);
            if (mode == 1) {
                float* ct = xs + 2048;           // [32][9] padded, 288 fl
                ct[p * 9 + rr] = c;
                __syncthreads();
                if (tid < 32) {
                    const float* sp = ct + tid * 9;
                    float4 A  = { sp[0], sp[1], sp[2], sp[3] };
                    float4 Bv = { sp[4], sp[5], sp[6], sp[7] };
                    float4* dst = (float4*)(phasorT +
                        ((size_t)(bq * P_ + tid)) * L_ + row0l);
                    dst[0] = A; dst[1] = Bv;
                }
            } else {
                float2* ct2 = (float2*)(xs + 2048);  // [32][9] f2, 576 fl
                ct2[p * 9 + rr] = make_float2(c, s);
                __syncthreads();
                if (tid < 32) {
                    const float2* sp = ct2 + tid * 9;
                    float4* dst = (float4*)((float2*)phasorT +
                        ((size_t)(bq * P_ + tid)) * L_ + row0l);
                    dst[0] = make_float4(sp[0].x, sp[0].y, sp[1].x, sp[1].y);
                    dst[1] = make_float4(sp[2].x, sp[2].y, sp[3].x, sp[3].y);
                    dst[2] = make_float4(sp[4].x, sp[4].y, sp[5].x, sp[5].y);
                    dst[3] = make_float4(sp[6].x, sp[6].y, sp[7].x, sp[7].y);
                }
            }
        }
    }
}

// ---------------------------------------------------------------------------
// Value-reuse chunk partials (round-6). Blocks = (b, c, ds): 256 blocks x 256
// threads; ds in [0,8) owns 16 float2-columns. Stage the chunk's values slice
// (8 KB) + ALL 32 p phasors (8 KB, pad 33 vs bank conflicts) in LDS once;
// compute S for all 32 p. values read ONCE total (2 MB, was 64 MB = 32x
// redundant). Output layout byte-identical to k_scan's reader.
// ---------------------------------------------------------------------------
__global__ __launch_bounds__(256) void k_partial2(
    const float* __restrict__ values, const float* __restrict__ phasorT,
    float* __restrict__ S, int mode)
{
    const int blk = blockIdx.x;                  // b*C_*8 + c*8 + ds
    const int ds  = blk & 7;
    const int c   = (blk >> 3) & (C_ - 1);
    const int b   = blk >> 7;
    const int tid = threadIdx.x;                 // 0..255
    const int l0  = c * CL_;

    __shared__ float smem2[2048 + 64 * 33 * 2];  // vs 8 KB + pcs up to 16.5 KB
    float2* vs   = (float2*)smem2;               // [64][16] float2
    float*  pcs  = smem2 + 2048;                 // mode 1: [64][33] float
    float2* pcs2 = (float2*)(smem2 + 2048);      // mode 0: [64][33] float2

    // stage values slice: rows l0..l0+63, float2 cols [ds*16, ds*16+16)
    const float2* vg = (const float2*)values;
    #pragma unroll
    for (int k = 0; k < 4; ++k) {
        const int lin = tid + k * 256;           // 0..1023
        const int i = lin >> 4, jj = lin & 15;
        vs[i * 16 + jj] =
            vg[(size_t)(b * L_ + l0 + i) * (D_/2) + ds * 16 + jj];
    }
    // stage phasors for all 32 p (transposed into [i][p], pad 33)
    if (mode == 1) {
        #pragma unroll
        for (int k = 0; k < 8; ++k) {
            const int lin = tid + k * 256;       // 0..2047
            const int p = lin >> 6, i = lin & 63;
            pcs[i * 33 + p] = phasorT[((size_t)b * P_ + p) * L_ + l0 + i];
        }
    } else {
        #pragma unroll
        for (int k = 0; k < 8; ++k) {
            const int lin = tid + k * 256;
            const int p = lin >> 6, i = lin & 63;
            pcs2[i * 33 + p] =
                ((const float2*)phasorT)[((size_t)b * P_ + p) * L_ + l0 + i];
        }
    }
    __syncthreads();

    const int p  = tid >> 3;                     // 0..31
    const int cp = tid & 7;                      // col pair -> f2 cols cp*2, cp*2+1

    if (mode == 1) {
        float sx0 = 0.f, sy0 = 0.f, sx1 = 0.f, sy1 = 0.f;
        #pragma unroll 8
        for (int i = 0; i < CL_; ++i) {
            float  pc = pcs[i * 33 + p];         // bcast in 8-lane p-group
            float2 v0 = vs[i * 16 + cp * 2];     // conflict-free b64
            float2 v1 = vs[i * 16 + cp * 2 + 1];
            sx0 += pc * v0.x; sy0 += pc * v0.y;
            sx1 += pc * v1.x; sy1 += pc * v1.y;
        }
        // S float2 idx = (bp*C_+c)*128 + ds*16 + cp*2  -> float4 store
        float4 o = make_float4(sx0, sy0, sx1, sy1);
        ((float4*)S)[((size_t)(b * P_ + p) * C_ + c) * 64 + ds * 8 + cp] = o;
    } else {
        float4 a0 = make_float4(0.f,0.f,0.f,0.f);
        float4 a1 = make_float4(0.f,0.f,0.f,0.f);
        #pragma unroll 8
        for (int i = 0; i < CL_; ++i) {
            float2 q  = pcs2[i * 33 + p];
            float2 v0 = vs[i * 16 + cp * 2];
            float2 v1 = vs[i * 16 + cp * 2 + 1];
            a0.x += q.x * v0.x; a0.y += q.y * v0.x;
            a0.z += q.x * v0.y; a0.w += q.y * v0.y;
            a1.x += q.x * v1.x; a1.y += q.y * v1.x;
            a1.z += q.x * v1.y; a1.w += q.y * v1.y;
        }
        const size_t base =
            ((size_t)(b * P_ + p) * C_ + c) * (D_/2) + ds * 16 + cp * 2;
        ((float4*)S)[base]     = a0;
        ((float4*)S)[base + 1] = a1;
    }
}

// ---------------------------------------------------------------------------
// Fallback chunk partials (no phasorT in ws). 1024 blocks x 128.
// ---------------------------------------------------------------------------
__global__ __launch_bounds__(128) void k_partial(
    const float* __restrict__ values, const float* __restrict__ phases,
    float* __restrict__ S, int mode)
{
    const int blk = blockIdx.x;                  // b*P_*C_ + p*C_ + c
    const int c = blk & (C_ - 1);
    const int p = (blk >> 4) & (P_ - 1);
    const int b = blk >> 9;
    const int tid = threadIdx.x;                 // 0..127
    const int l0 = c * CL_;
    const int bp = b * P_ + p;

    __shared__ float pcs[2 * CL_];
    if (tid < CL_) {
        float ph = phases[(b * L_ + l0 + tid) * P_ + p];
        if (mode == 1) pcs[tid] = __cosf(ph);
        else ((float2*)pcs)[tid] = make_float2(__cosf(ph), __sinf(ph));
    }
    __syncthreads();

    const float2* vp = (const float2*)(values + (size_t)(b * L_ + l0) * D_) + tid;

    if (mode == 1) {
        float sx = 0.f, sy = 0.f;
        #pragma unroll
        for (int i = 0; i < CL_; ++i) {
            float pc = pcs[i];
            float2 v = vp[(size_t)i * (D_/2)];
            sx += pc * v.x;
            sy += pc * v.y;
        }
        ((float2*)S)[((size_t)bp * C_ + c) * (D_/2) + tid] = make_float2(sx, sy);
    } else {
        float4 a = make_float4(0.f, 0.f, 0.f, 0.f);
        #pragma unroll
        for (int i = 0; i < CL_; ++i) {
            float2 q = ((float2*)pcs)[i];
            float2 v = vp[(size_t)i * (D_/2)];
            a.x += q.x * v.x; a.y += q.y * v.x;
            a.z += q.x * v.y; a.w += q.y * v.y;
        }
        ((float4*)S)[((size_t)bp * C_ + c) * (D_/2) + tid] = a;
    }
}

// ---------------------------------------------------------------------------
// Scan: carry = sum of <=15 chunk partials (independent loads), then uniform
// 64-step running sum + NT store. 1024 blocks x 128. AT the write roofline
// (64 MiB at ~5.8 TB/s demonstrated) — do not touch.
// ---------------------------------------------------------------------------
__global__ __launch_bounds__(128) void k_scan(
    const float* __restrict__ values, const float* __restrict__ phases,
    const float* __restrict__ phasorT, const float* __restrict__ S,
    float* __restrict__ mem, int mode, int hasPT)
{
    const int blk = blockIdx.x;
    const int c = blk & (C_ - 1);
    const int p = (blk >> 4) & (P_ - 1);
    const int b = blk >> 9;
    const int tid = threadIdx.x;
    const int l0 = c * CL_;
    const int bp = b * P_ + p;

    __shared__ float pcs[2 * CL_];
    if (hasPT) {
        if (mode == 1) {
            if (tid < CL_ / 4)
                ((float4*)pcs)[tid] =
                    ((const float4*)(phasorT + (size_t)bp * L_ + l0))[tid];
        } else {
            if (tid < CL_ / 2)
                ((float4*)pcs)[tid] = ((const float4*)
                    ((const float2*)phasorT + (size_t)bp * L_ + l0))[tid];
        }
    } else {
        if (tid < CL_) {
            float ph = phases[(b * L_ + l0 + tid) * P_ + p];
            if (mode == 1) pcs[tid] = __cosf(ph);
            else ((float2*)pcs)[tid] = make_float2(__cosf(ph), __sinf(ph));
        }
    }

    const float2* vp = (const float2*)(values + (size_t)(b * L_ + l0) * D_) + tid;

    if (mode == 1) {
        float cx = 0.f, cz = 0.f;
        const float2* Sb = (const float2*)S + (size_t)bp * C_ * (D_/2) + tid;
        for (int cc = 0; cc < c; ++cc) {         // <=15 independent loads
            float2 s = Sb[(size_t)cc * (D_/2)];
            cx += s.x; cz += s.y;
        }
        __syncthreads();
        nvf2* dst = (nvf2*)mem + ((size_t)(b * L_ + l0) * P_ + p) * (D_/2) + tid;
        const size_t st = (size_t)P_ * (D_/2);   // row stride in float2
        #pragma unroll
        for (int i = 0; i < CL_; ++i) {
            float pc = pcs[i];
            float2 v = vp[(size_t)i * (D_/2)];   // L2-hot
            cx += pc * v.x;
            cz += pc * v.y;
            nvf2 o = { cx, cz };
            __builtin_nontemporal_store(o, dst + (size_t)i * st);
        }
    } else {
        float4 carry = make_float4(0.f, 0.f, 0.f, 0.f);
        const float4* Sb = (const float4*)S + (size_t)bp * C_ * (D_/2) + tid;
        for (int cc = 0; cc < c; ++cc) {
            float4 s = Sb[(size_t)cc * (D_/2)];
            carry.x += s.x; carry.y += s.y; carry.z += s.z; carry.w += s.w;
        }
        __syncthreads();
        nvf4* dst = (nvf4*)mem + ((size_t)(b * L_ + l0) * P_ + p) * (D_/2) + tid;
        const size_t st = (size_t)P_ * (D_/2);
        #pragma unroll
        for (int i = 0; i < CL_; ++i) {
            float2 q = ((float2*)pcs)[i];
            float2 v = vp[(size_t)i * (D_/2)];
            carry.x += q.x * v.x; carry.y += q.y * v.x;
            carry.z += q.x * v.y; carry.w += q.y * v.y;
            nvf4 o = { carry.x, carry.y, carry.z, carry.w };
            __builtin_nontemporal_store(o, dst + (size_t)i * st);
        }
    }
}

// ---------------------------------------------------------------------------
// Path B parachute (small ws): carry recomputed from values/phases via L2.
// ---------------------------------------------------------------------------
__global__ __launch_bounds__(128) void k_scan_rc(
    const float* __restrict__ values, const float* __restrict__ phases,
    float* __restrict__ mem, int mode)
{
    const int blk = blockIdx.x;
    const int c = blk & (C_ - 1);
    const int p = (blk >> 4) & (P_ - 1);
    const int b = blk >> 9;
    const int tid = threadIdx.x;
    const int l0 = c * CL_;

    const float2* vb = (const float2*)(values + (size_t)b * L_ * D_);
    float4 carry = make_float4(0.f, 0.f, 0.f, 0.f);
    for (int l = 0; l < l0; ++l) {
        float ph = phases[(b * L_ + l) * P_ + p];
        float s = __sinf(ph), cs = __cosf(ph);
        float2 v = vb[l * (D_/2) + tid];
        carry.x += cs * v.x; carry.y += s * v.x;
        carry.z += cs * v.y; carry.w += s * v.y;
    }
    for (int i = 0; i < CL_; ++i) {
        const int l = l0 + i;
        float ph = phases[(b * L_ + l) * P_ + p];
        float s = __sinf(ph), cs = __cosf(ph);
        float2 v = vb[l * (D_/2) + tid];
        carry.x += cs * v.x; carry.y += s * v.x;
        carry.z += cs * v.y; carry.w += s * v.y;
        const size_t rowIdx = (size_t)(b * L_ + l) * P_ + p;
        if (mode == 0) ((float4*)mem)[rowIdx * (D_/2) + tid] = carry;
        else ((float2*)mem)[rowIdx * (D_/2) + tid] = make_float2(carry.x, carry.z);
    }
}

extern "C" void kernel_launch(void* const* d_in, const int* in_sizes, int n_in,
                              void* d_out, int out_size, void* d_ws, size_t ws_size,
                              hipStream_t stream) {
    const float* x  = (const float*)d_in[0];
    const float* Wp = (const float*)d_in[1];
    const float* bp = (const float*)d_in[2];
    const float* Wv = (const float*)d_in[3];
    const float* bv = (const float*)d_in[4];
    float* out = (float*)d_out;

    const size_t nMemF = (size_t)2 * B_ * L_ * P_ * D_;  // 33554432 (interleaved)
    const size_t nMemR = (size_t)B_ * L_ * P_ * D_;      // 16777216 (real only)
    const size_t nPh   = (size_t)B_ * L_ * P_;           // 65536

    // Output layout mode by out_size. Round-2/3 counter evidence: scan
    // WRITE_SIZE = 64 MiB = nMemR*4B => harness runs mode 1.
    int mode; size_t memFloats;
    if ((size_t)out_size >= nMemF + 3 * nPh) { mode = 0; memFloats = nMemF; }
    else                                     { mode = 1; memFloats = nMemR; }
    const bool memFits      = (size_t)out_size >= memFloats;
    const bool phasesInOut  = (size_t)out_size >= memFloats + nPh;
    const bool phasorsInOut =
        (size_t)out_size >= memFloats + nPh + (mode == 0 ? 2 * nPh : nPh);

    // ws layout: values | phasesWs | S | phasorT
    const size_t valB = (size_t)B_ * L_ * D_ * sizeof(float);                // 2 MB
    const size_t phB  = nPh * sizeof(float);                                 // 256 KB
    const size_t sB   = (size_t)B_ * P_ * C_ * (D_/2) * sizeof(float4);      // 2 MB (mode0 max)
    const size_t ptB  = nPh * (mode == 0 ? sizeof(float2) : sizeof(float));  // 512/256 KB
    float* values   = (float*)d_ws;
    float* phasesWs = (float*)((char*)d_ws + valB);
    float* S        = (float*)((char*)d_ws + valB + phB);
    float* phasorT  = (float*)((char*)d_ws + valB + phB + sB);

    float* phasesPtr = phasesInOut ? (out + memFloats)
                     : (ws_size >= valB + phB ? phasesWs : nullptr);
    if (phasesPtr == nullptr) return;            // unreachable (ws verified big enough)

    float* phasorPtr = phasorsInOut ? (out + memFloats + nPh) : nullptr;
    const int phasorMode = phasorsInOut ? mode : 2;

    const bool pathA = ws_size >= valB + phB + sB;           // partials fit
    const int  hasPT = (pathA && ws_size >= valB + phB + sB + ptB) ? 1 : 0;

    k_proj3<<<NROW / 2 + NROW / 8, 256, 0, stream>>>(
        x, Wp, bp, Wv, bv, values, phasesPtr, phasorPtr, phasorT,
        phasorMode, mode, hasPT);
    if (!memFits) return;

    if (pathA) {
        if (hasPT) {
            k_partial2<<<B_ * C_ * 8, 256, 0, stream>>>(values, phasorT, S, mode);
        } else {
            k_partial<<<B_ * P_ * C_, 128, 0, stream>>>(values, phasesPtr, S, mode);
        }
        k_scan<<<B_ * P_ * C_, 128, 0, stream>>>(values, phasesPtr, phasorT,
                                                 S, out, mode, hasPT);
    } else {
        k_scan_rc<<<B_ * P_ * C_, 128, 0, stream>>>(values, phasesPtr, out, mode);
    }
}

// Round 7
// 104.554 us; speedup vs baseline: 1.0327x; 1.0327x over previous
//
#include <hip/hip_runtime.h>
#include <math.h>

// Problem constants (from reference): B=2, L=1024, D=256, P=32
#define B_ 2
#define L_ 1024
#define D_ 256
#define P_ 32
#define NROW (B_*L_)          // 2048 flattened (b,l) rows
#define C_ 16                 // L chunks for the scan
#define CL_ (L_/C_)           // 64 positions per chunk
#define PIF 3.14159265358979323846f

// Native clang vector types — required by __builtin_nontemporal_store
typedef float nvf4 __attribute__((ext_vector_type(4)));
typedef float nvf2 __attribute__((ext_vector_type(2)));

// ---------------------------------------------------------------------------
// Budget model (rounds 5-6 calibrated): ~69 us fixed harness fills per iter
// + scan ~12 us (AT write roofline) + proj ~10-13 + partial ~2-3 + gaps ~6-9.
// Round-7: fuse partial+scan into ONE kernel (block-internal chunk prefix,
// no cross-block coupling) — removes a launch gap + the S global round-trip.
// Round-2 lesson: NO agent-scope atomics (per-XCD L2 invalidation storm).
// Round-4 lesson: keep per-block work UNIFORM (no triangular tails).
// ---------------------------------------------------------------------------

// ---------------------------------------------------------------------------
// Projection kernel, 1280 blocks x 256 threads.
//  blocks [0, 1024): values GEMM, 2 rows/block, K-SPLIT: quarter-wave q owns
//    k in [64q, 64q+64); partials reduced through 8 KB LDS.
//  blocks [1024, 1280): phase GEMM, 8 rows x 32 p; fast tanh via __expf and
//    __sincosf; phases -> out, phasors -> out, transposed phasor copy via
//    LDS transpose (coalesced 32/64-B runs per p):
//      mode 1: phasorT is float  cos-only  [bp*L + l]   (256 KB)
//      mode 0: phasorT is float2 (cos,sin) [bp*L + l]   (512 KB)
// phasorMode: 0 = float2 (cos,sin), 1 = cos only, 2 = skip. hasPT: write pT.
// ---------------------------------------------------------------------------
__global__ __launch_bounds__(256) void k_proj3(
    const float* __restrict__ x, const float* __restrict__ Wp,
    const float* __restrict__ bp, const float* __restrict__ Wv,
    const float* __restrict__ bv, float* __restrict__ values,
    float* __restrict__ phases_out, float* __restrict__ phasor_out,
    float* __restrict__ phasorT, int phasorMode, int mode, int hasPT)
{
    __shared__ float smem[3072];                 // 12 KB carved below
    const int tid = threadIdx.x;

    if (blockIdx.x < NROW / 2) {
        // ---- values: rows [row0, row0+2), K-split ----
        const int row0 = blockIdx.x * 2;
        float*  xsv = smem;                      // 512 floats (2 KB)
        float4* red = (float4*)(smem + 512);     // 512 float4 (8 KB)

        if (tid < 128)
            ((float4*)xsv)[tid] = ((const float4*)(x + (size_t)row0 * D_))[tid];
        __syncthreads();

        const int q  = tid >> 6;                 // k-quarter, wave-uniform
        const int c4 = tid & 63;                 // float4 column group
        const float4* Wv4 = (const float4*)Wv;
        float4 acc0 = make_float4(0.f, 0.f, 0.f, 0.f);
        float4 acc1 = make_float4(0.f, 0.f, 0.f, 0.f);

        const int k0 = q * 64;
        for (int kk = 0; kk < 64; kk += 4) {
            const int k = k0 + kk;
            float4 w0 = Wv4[(k + 0) * 64 + c4]; // coalesced 1KB/wave
            float4 w1 = Wv4[(k + 1) * 64 + c4];
            float4 w2 = Wv4[(k + 2) * 64 + c4];
            float4 w3 = Wv4[(k + 3) * 64 + c4];
            float4 xa = *(const float4*)(xsv + 0 * D_ + k);  // bcast b128
            float4 xb = *(const float4*)(xsv + 1 * D_ + k);
            acc0.x += xa.x*w0.x + xa.y*w1.x + xa.z*w2.x + xa.w*w3.x;
            acc0.y += xa.x*w0.y + xa.y*w1.y + xa.z*w2.y + xa.w*w3.y;
            acc0.z += xa.x*w0.z + xa.y*w1.z + xa.z*w2.z + xa.w*w3.z;
            acc0.w += xa.x*w0.w + xa.y*w1.w + xa.z*w2.w + xa.w*w3.w;
            acc1.x += xb.x*w0.x + xb.y*w1.x + xb.z*w2.x + xb.w*w3.x;
            acc1.y += xb.x*w0.y + xb.y*w1.y + xb.z*w2.y + xb.w*w3.y;
            acc1.z += xb.x*w0.z + xb.y*w1.z + xb.z*w2.z + xb.w*w3.z;
            acc1.w += xb.x*w0.w + xb.y*w1.w + xb.z*w2.w + xb.w*w3.w;
        }
        red[(0 * 4 + q) * 64 + c4] = acc0;
        red[(1 * 4 + q) * 64 + c4] = acc1;
        __syncthreads();

        if (tid < 128) {
            const int r2 = tid >> 6;             // row this thread finalizes
            const int cb = tid & 63;
            float4 s0 = red[(r2 * 4 + 0) * 64 + cb];
            float4 s1 = red[(r2 * 4 + 1) * 64 + cb];
            float4 s2 = red[(r2 * 4 + 2) * 64 + cb];
            float4 s3 = red[(r2 * 4 + 3) * 64 + cb];
            const float4 b4 = ((const float4*)bv)[cb];
            float4 o;
            o.x = s0.x + s1.x + s2.x + s3.x + b4.x;
            o.y = s0.y + s1.y + s2.y + s3.y + b4.y;
            o.z = s0.z + s1.z + s2.z + s3.z + b4.z;
            o.w = s0.w + s1.w + s2.w + s3.w + b4.w;
            ((float4*)values)[(size_t)(row0 + r2) * 64 + cb] = o;
        }
    } else {
        // ---- phases/phasors: rows [row0, row0+8) ----
        const int row0 = (blockIdx.x - NROW / 2) * 8;
        float* xs = smem;                        // 2048 floats (8 KB)
        const float4* xg4 = (const float4*)(x + (size_t)row0 * D_);
        ((float4*)xs)[tid]       = xg4[tid];
        ((float4*)xs)[tid + 256] = xg4[tid + 256];
        __syncthreads();

        const int p  = tid & (P_ - 1);
        const int rr = tid >> 5;                 // 0..7
        const float* xr = xs + rr * D_;
        float a0 = 0.f, a1 = 0.f, a2 = 0.f, a3 = 0.f;
        for (int k = 0; k < D_; k += 8) {
            float w0 = Wp[(k + 0) * P_ + p];
            float w1 = Wp[(k + 1) * P_ + p];
            float w2 = Wp[(k + 2) * P_ + p];
            float w3 = Wp[(k + 3) * P_ + p];
            float w4 = Wp[(k + 4) * P_ + p];
            float w5 = Wp[(k + 5) * P_ + p];
            float w6 = Wp[(k + 6) * P_ + p];
            float w7 = Wp[(k + 7) * P_ + p];
            float4 xA = *(const float4*)(xr + k);
            float4 xB = *(const float4*)(xr + k + 4);
            a0 += xA.x * w0; a1 += xA.y * w1; a2 += xA.z * w2; a3 += xA.w * w3;
            a0 += xB.x * w4; a1 += xB.y * w5; a2 += xB.z * w6; a3 += xB.w * w7;
        }
        float a = (a0 + a1) + (a2 + a3) + bp[p];
        // fast tanh: 1 - 2/(e^{2a}+1); inf-safe at both extremes
        float e  = __expf(2.0f * a);
        float ph = (1.0f - __fdividef(2.0f, e + 1.0f)) * PIF;
        const int row = row0 + rr;
        const int idx = row * P_ + p;
        phases_out[idx] = ph;
        float s, c;
        __sincosf(ph, &s, &c);
        if (phasorMode == 0) {
            ((float2*)phasor_out)[idx] = make_float2(c, s);
        } else if (phasorMode == 1) {
            phasor_out[idx] = c;
        }
        // ---- phasorT via LDS transpose (coalesced 32/64-B runs per p) ----
        if (hasPT) {
            const int bq    = row0 >> 10;        // block never crosses b
            const int row0l = row0 & (L_ - 1);
            if (mode == 1) {
                float* ct = xs + 2048;           // [32][9] padded, 288 fl
                ct[p * 9 + rr] = c;
                __syncthreads();
                if (tid < 32) {
                    const float* sp = ct + tid * 9;
                    float4 A  = { sp[0], sp[1], sp[2], sp[3] };
                    float4 Bv = { sp[4], sp[5], sp[6], sp[7] };
                    float4* dst = (float4*)(phasorT +
                        ((size_t)(bq * P_ + tid)) * L_ + row0l);
                    dst[0] = A; dst[1] = Bv;
                }
            } else {
                float2* ct2 = (float2*)(xs + 2048);  // [32][9] f2, 576 fl
                ct2[p * 9 + rr] = make_float2(c, s);
                __syncthreads();
                if (tid < 32) {
                    const float2* sp = ct2 + tid * 9;
                    float4* dst = (float4*)((float2*)phasorT +
                        ((size_t)(bq * P_ + tid)) * L_ + row0l);
                    dst[0] = make_float4(sp[0].x, sp[0].y, sp[1].x, sp[1].y);
                    dst[1] = make_float4(sp[2].x, sp[2].y, sp[3].x, sp[3].y);
                    dst[2] = make_float4(sp[4].x, sp[4].y, sp[5].x, sp[5].y);
                    dst[3] = make_float4(sp[6].x, sp[6].y, sp[7].x, sp[7].y);
                }
            }
        }
    }
}

// ---------------------------------------------------------------------------
// Fused partial+scan, block-INTERNAL prefix (round-7). Grid (b, p, d8):
// 512 blocks x 256 threads; thread = (slot in [0,16), col in [0,16)).
// Block owns a 16-float2 D-slice of one (b,p) across the FULL L:
//  stage:  all 1024 phasors for (b,p) into LDS (coalesced float4)
//  phase1: thread computes chunk `slot`'s partial (uniform 64 iters, L2-hot
//          values loads) -> LDS part[16][16]; barrier
//  prefix: carry = sum part[cc<slot][col]  (<=15 LDS reads, block-local!)
//  phase2: 64-step running scan + NT store (128-B runs per 16-lane group,
//          d8 blocks tile the full 1-KB row)
// No cross-block sync, no S global round-trip, uniform work, one less launch.
// Occupancy: 2 blocks/CU x 4 waves = 8 waves/CU — same as the roofline scan.
// ---------------------------------------------------------------------------
__global__ __launch_bounds__(256) void k_pscan(
    const float* __restrict__ values, const float* __restrict__ phases,
    const float* __restrict__ phasorT, float* __restrict__ mem,
    int mode, int hasPT)
{
    const int blk  = blockIdx.x;                 // b*P_*8 + p*8 + d8
    const int d8   = blk & 7;
    const int p    = (blk >> 3) & (P_ - 1);
    const int b    = blk >> 8;
    const int tid  = threadIdx.x;                // 0..255
    const int col  = tid & 15;
    const int slot = tid >> 4;                   // chunk index 0..15
    const int bp   = b * P_ + p;
    const int l0   = slot * CL_;

    __shared__ float sm[3072];                   // 12 KB max (mode 0)
    float*  pcs   = sm;                          // mode1: [1024] cos
    float2* pcs2  = (float2*)sm;                 // mode0: [1024] (cos,sin)
    float2* part2 = (float2*)(sm + 1024);        // mode1 partials [16][16]
    float4* part4 = (float4*)(sm + 2048);        // mode0 partials [16][16]

    if (hasPT) {
        if (mode == 1) {
            ((float4*)pcs)[tid] =
                ((const float4*)(phasorT + (size_t)bp * L_))[tid];   // 1024 fl
        } else {
            const float4* src =
                (const float4*)((const float2*)phasorT + (size_t)bp * L_);
            ((float4*)pcs2)[tid]       = src[tid];
            ((float4*)pcs2)[tid + 256] = src[tid + 256];
        }
    } else {
        for (int l = tid; l < L_; l += 256) {
            float ph = phases[(b * L_ + l) * P_ + p];
            if (mode == 1) pcs[l] = __cosf(ph);
            else           pcs2[l] = make_float2(__cosf(ph), __sinf(ph));
        }
    }
    __syncthreads();

    const float2* vbase =
        (const float2*)values + (size_t)(b * L_) * (D_/2) + d8 * 16 + col;

    if (mode == 1) {
        // ---- phase 1: chunk partial (independent iters, good ILP) ----
        float sx = 0.f, sy = 0.f;
        #pragma unroll 8
        for (int i = 0; i < CL_; ++i) {
            float  pc = pcs[l0 + i];             // bcast per 16-lane group
            float2 v  = vbase[(size_t)(l0 + i) * (D_/2)];
            sx += pc * v.x;
            sy += pc * v.y;
        }
        part2[slot * 16 + col] = make_float2(sx, sy);
        __syncthreads();

        // ---- block-local prefix: <=15 LDS reads ----
        float cx = 0.f, cz = 0.f;
        for (int cc = 0; cc < slot; ++cc) {
            float2 s = part2[cc * 16 + col];
            cx += s.x; cz += s.y;
        }

        // ---- phase 2: running scan + NT store ----
        nvf2* dst = (nvf2*)mem +
            ((size_t)(b * L_ + l0) * P_ + p) * (D_/2) + d8 * 16 + col;
        const size_t st = (size_t)P_ * (D_/2);   // l-row stride in float2
        #pragma unroll 8
        for (int i = 0; i < CL_; ++i) {
            float  pc = pcs[l0 + i];
            float2 v  = vbase[(size_t)(l0 + i) * (D_/2)];  // L2-hot (phase 1)
            cx += pc * v.x;
            cz += pc * v.y;
            nvf2 o = { cx, cz };
            __builtin_nontemporal_store(o, dst + (size_t)i * st);
        }
    } else {
        float4 a = make_float4(0.f, 0.f, 0.f, 0.f);
        #pragma unroll 8
        for (int i = 0; i < CL_; ++i) {
            float2 q = pcs2[l0 + i];
            float2 v = vbase[(size_t)(l0 + i) * (D_/2)];
            a.x += q.x * v.x; a.y += q.y * v.x;
            a.z += q.x * v.y; a.w += q.y * v.y;
        }
        part4[slot * 16 + col] = a;
        __syncthreads();

        float4 carry = make_float4(0.f, 0.f, 0.f, 0.f);
        for (int cc = 0; cc < slot; ++cc) {
            float4 s = part4[cc * 16 + col];
            carry.x += s.x; carry.y += s.y; carry.z += s.z; carry.w += s.w;
        }

        nvf4* dst = (nvf4*)mem +
            ((size_t)(b * L_ + l0) * P_ + p) * (D_/2) + d8 * 16 + col;
        const size_t st = (size_t)P_ * (D_/2);   // l-row stride in float4
        #pragma unroll 8
        for (int i = 0; i < CL_; ++i) {
            float2 q = pcs2[l0 + i];
            float2 v = vbase[(size_t)(l0 + i) * (D_/2)];
            carry.x += q.x * v.x; carry.y += q.y * v.x;
            carry.z += q.x * v.y; carry.w += q.y * v.y;
            nvf4 o = { carry.x, carry.y, carry.z, carry.w };
            __builtin_nontemporal_store(o, dst + (size_t)i * st);
        }
    }
}

// ---------------------------------------------------------------------------
// Path B parachute (small ws): carry recomputed from values/phases via L2.
// ---------------------------------------------------------------------------
__global__ __launch_bounds__(128) void k_scan_rc(
    const float* __restrict__ values, const float* __restrict__ phases,
    float* __restrict__ mem, int mode)
{
    const int blk = blockIdx.x;
    const int c = blk & (C_ - 1);
    const int p = (blk >> 4) & (P_ - 1);
    const int b = blk >> 9;
    const int tid = threadIdx.x;
    const int l0 = c * CL_;

    const float2* vb = (const float2*)(values + (size_t)b * L_ * D_);
    float4 carry = make_float4(0.f, 0.f, 0.f, 0.f);
    for (int l = 0; l < l0; ++l) {
        float ph = phases[(b * L_ + l) * P_ + p];
        float s = __sinf(ph), cs = __cosf(ph);
        float2 v = vb[l * (D_/2) + tid];
        carry.x += cs * v.x; carry.y += s * v.x;
        carry.z += cs * v.y; carry.w += s * v.y;
    }
    for (int i = 0; i < CL_; ++i) {
        const int l = l0 + i;
        float ph = phases[(b * L_ + l) * P_ + p];
        float s = __sinf(ph), cs = __cosf(ph);
        float2 v = vb[l * (D_/2) + tid];
        carry.x += cs * v.x; carry.y += s * v.x;
        carry.z += cs * v.y; carry.w += s * v.y;
        const size_t rowIdx = (size_t)(b * L_ + l) * P_ + p;
        if (mode == 0) ((float4*)mem)[rowIdx * (D_/2) + tid] = carry;
        else ((float2*)mem)[rowIdx * (D_/2) + tid] = make_float2(carry.x, carry.z);
    }
}

extern "C" void kernel_launch(void* const* d_in, const int* in_sizes, int n_in,
                              void* d_out, int out_size, void* d_ws, size_t ws_size,
                              hipStream_t stream) {
    const float* x  = (const float*)d_in[0];
    const float* Wp = (const float*)d_in[1];
    const float* bp = (const float*)d_in[2];
    const float* Wv = (const float*)d_in[3];
    const float* bv = (const float*)d_in[4];
    float* out = (float*)d_out;

    const size_t nMemF = (size_t)2 * B_ * L_ * P_ * D_;  // 33554432 (interleaved)
    const size_t nMemR = (size_t)B_ * L_ * P_ * D_;      // 16777216 (real only)
    const size_t nPh   = (size_t)B_ * L_ * P_;           // 65536

    // Output layout mode by out_size. Round-2/3 counter evidence: scan
    // WRITE_SIZE = 64 MiB = nMemR*4B => harness runs mode 1.
    int mode; size_t memFloats;
    if ((size_t)out_size >= nMemF + 3 * nPh) { mode = 0; memFloats = nMemF; }
    else                                     { mode = 1; memFloats = nMemR; }
    const bool memFits      = (size_t)out_size >= memFloats;
    const bool phasesInOut  = (size_t)out_size >= memFloats + nPh;
    const bool phasorsInOut =
        (size_t)out_size >= memFloats + nPh + (mode == 0 ? 2 * nPh : nPh);

    // ws layout: values | phasesWs | S(hole, legacy offset) | phasorT
    const size_t valB = (size_t)B_ * L_ * D_ * sizeof(float);                // 2 MB
    const size_t phB  = nPh * sizeof(float);                                 // 256 KB
    const size_t sB   = (size_t)B_ * P_ * C_ * (D_/2) * sizeof(float4);      // 2 MB hole
    const size_t ptB  = nPh * (mode == 0 ? sizeof(float2) : sizeof(float));  // 512/256 KB
    float* values   = (float*)d_ws;
    float* phasesWs = (float*)((char*)d_ws + valB);
    float* phasorT  = (float*)((char*)d_ws + valB + phB + sB);

    float* phasesPtr = phasesInOut ? (out + memFloats)
                     : (ws_size >= valB + phB ? phasesWs : nullptr);
    if (phasesPtr == nullptr) return;            // unreachable (ws verified big enough)

    float* phasorPtr = phasorsInOut ? (out + memFloats + nPh) : nullptr;
    const int phasorMode = phasorsInOut ? mode : 2;

    const bool pathA = ws_size >= valB + phB;                // values+phases fit
    const int  hasPT = (ws_size >= valB + phB + sB + ptB) ? 1 : 0;

    k_proj3<<<NROW / 2 + NROW / 8, 256, 0, stream>>>(
        x, Wp, bp, Wv, bv, values, phasesPtr, phasorPtr, phasorT,
        phasorMode, mode, hasPT);
    if (!memFits) return;

    if (pathA) {
        k_pscan<<<B_ * P_ * 8, 256, 0, stream>>>(values, phasesPtr, phasorT,
                                                 out, mode, hasPT);
    } else {
        k_scan_rc<<<B_ * P_ * C_, 128, 0, stream>>>(values, phasesPtr, out, mode);
    }
}

// Round 8
// 99.801 us; speedup vs baseline: 1.0819x; 1.0476x over previous
//
#include <hip/hip_runtime.h>
#include <math.h>

// Problem constants (from reference): B=2, L=1024, D=256, P=32
#define B_ 2
#define L_ 1024
#define D_ 256
#define P_ 32
#define NROW (B_*L_)          // 2048 flattened (b,l) rows
#define C_ 16                 // L chunks for the scan
#define CL_ (L_/C_)           // 64 positions per chunk
#define PIF 3.14159265358979323846f

// Native clang vector types — required by __builtin_nontemporal_store
typedef float nvf4 __attribute__((ext_vector_type(4)));
typedef float nvf2 __attribute__((ext_vector_type(2)));

// ---------------------------------------------------------------------------
// Budget model (rounds 5-7 calibrated): ~69 us fixed harness fills per iter
// + k_pscan ~14-15 (floor 11.3 = 64 MiB NT write @ 5.9 TB/s) + proj ~11-13
// + 1 launch gap ~3-5.
// Round-8: proj values GEMM goes 2 -> 8 rows/block. With 2 rows, 1024 blocks
// each stream the full 256 KB Wv = 256 MB L2 reads (~7 us @ 36.9 TB/s) —
// 4x the 1.7 us VALU floor. 8 rows/block cuts Wv traffic to 64 MB (1.7 us).
// Round-2 lesson: NO agent-scope atomics (per-XCD L2 invalidation storm).
// Round-4 lesson: keep per-block work UNIFORM (no triangular tails).
// ---------------------------------------------------------------------------

// ---------------------------------------------------------------------------
// Projection kernel, 512 blocks x 256 threads.
//  blocks [0, 256): values GEMM, 8 rows/block, K-SPLIT: quarter-wave q owns
//    k in [64q, 64q+64); partial accs reduced through 32 KB LDS. Wv read
//    ONCE per block: 256 blocks x 256 KB = 64 MB L2 total (was 256 MB).
//  blocks [256, 512): phase GEMM, 8 rows x 32 p; fast tanh via __expf and
//    __sincosf; phases -> out, phasors -> out, transposed phasor copy via
//    LDS transpose (coalesced 32/64-B runs per p):
//      mode 1: phasorT is float  cos-only  [bp*L + l]   (256 KB)
//      mode 0: phasorT is float2 (cos,sin) [bp*L + l]   (512 KB)
// phasorMode: 0 = float2 (cos,sin), 1 = cos only, 2 = skip. hasPT: write pT.
// ---------------------------------------------------------------------------
__global__ __launch_bounds__(256) void k_proj3(
    const float* __restrict__ x, const float* __restrict__ Wp,
    const float* __restrict__ bp, const float* __restrict__ Wv,
    const float* __restrict__ bv, float* __restrict__ values,
    float* __restrict__ phases_out, float* __restrict__ phasor_out,
    float* __restrict__ phasorT, int phasorMode, int mode, int hasPT)
{
    __shared__ float smem[10240];                // 40 KB carved below
    const int tid = threadIdx.x;

    if (blockIdx.x < NROW / 8) {
        // ---- values: rows [row0, row0+8), K-split ----
        const int row0 = blockIdx.x * 8;
        float*  xsv = smem;                      // 2048 floats (8 KB)
        float4* red = (float4*)(smem + 2048);    // 2048 float4 (32 KB)

        const float4* xg4 = (const float4*)(x + (size_t)row0 * D_);
        ((float4*)xsv)[tid]       = xg4[tid];
        ((float4*)xsv)[tid + 256] = xg4[tid + 256];
        __syncthreads();

        const int q  = tid >> 6;                 // k-quarter, wave-uniform
        const int c4 = tid & 63;                 // float4 column group
        const float4* Wv4 = (const float4*)Wv;
        float4 acc[8];
        #pragma unroll
        for (int r = 0; r < 8; ++r) acc[r] = make_float4(0.f, 0.f, 0.f, 0.f);

        const int k0 = q * 64;
        for (int kk = 0; kk < 64; kk += 4) {
            const int k = k0 + kk;
            // 4 independent 16B Wv loads in flight (L2-resident per XCD)
            float4 w0 = Wv4[(k + 0) * 64 + c4]; // coalesced 1KB/wave
            float4 w1 = Wv4[(k + 1) * 64 + c4];
            float4 w2 = Wv4[(k + 2) * 64 + c4];
            float4 w3 = Wv4[(k + 3) * 64 + c4];
            #pragma unroll
            for (int r = 0; r < 8; ++r) {
                float4 xv = *(const float4*)(xsv + r * D_ + k);  // b128 bcast
                acc[r].x += xv.x*w0.x + xv.y*w1.x + xv.z*w2.x + xv.w*w3.x;
                acc[r].y += xv.x*w0.y + xv.y*w1.y + xv.z*w2.y + xv.w*w3.y;
                acc[r].z += xv.x*w0.z + xv.y*w1.z + xv.z*w2.z + xv.w*w3.z;
                acc[r].w += xv.x*w0.w + xv.y*w1.w + xv.z*w2.w + xv.w*w3.w;
            }
        }
        #pragma unroll
        for (int r = 0; r < 8; ++r) red[(r * 4 + q) * 64 + c4] = acc[r];
        __syncthreads();

        // 512 outputs (8 rows x 64 c4); 256 threads finalize 2 rows each
        const int cb = tid & 63;
        const float4 b4 = ((const float4*)bv)[cb];
        #pragma unroll
        for (int h = 0; h < 2; ++h) {
            const int r = (tid >> 6) + h * 4;    // rows 0..3 then 4..7
            float4 s0 = red[(r * 4 + 0) * 64 + cb];
            float4 s1 = red[(r * 4 + 1) * 64 + cb];
            float4 s2 = red[(r * 4 + 2) * 64 + cb];
            float4 s3 = red[(r * 4 + 3) * 64 + cb];
            float4 o;
            o.x = s0.x + s1.x + s2.x + s3.x + b4.x;
            o.y = s0.y + s1.y + s2.y + s3.y + b4.y;
            o.z = s0.z + s1.z + s2.z + s3.z + b4.z;
            o.w = s0.w + s1.w + s2.w + s3.w + b4.w;
            ((float4*)values)[(size_t)(row0 + r) * 64 + cb] = o;
        }
    } else {
        // ---- phases/phasors: rows [row0, row0+8) ----
        const int row0 = (blockIdx.x - NROW / 8) * 8;
        float* xs = smem;                        // 2048 floats (8 KB)
        const float4* xg4 = (const float4*)(x + (size_t)row0 * D_);
        ((float4*)xs)[tid]       = xg4[tid];
        ((float4*)xs)[tid + 256] = xg4[tid + 256];
        __syncthreads();

        const int p  = tid & (P_ - 1);
        const int rr = tid >> 5;                 // 0..7
        const float* xr = xs + rr * D_;
        float a0 = 0.f, a1 = 0.f, a2 = 0.f, a3 = 0.f;
        for (int k = 0; k < D_; k += 8) {
            float w0 = Wp[(k + 0) * P_ + p];
            float w1 = Wp[(k + 1) * P_ + p];
            float w2 = Wp[(k + 2) * P_ + p];
            float w3 = Wp[(k + 3) * P_ + p];
            float w4 = Wp[(k + 4) * P_ + p];
            float w5 = Wp[(k + 5) * P_ + p];
            float w6 = Wp[(k + 6) * P_ + p];
            float w7 = Wp[(k + 7) * P_ + p];
            float4 xA = *(const float4*)(xr + k);
            float4 xB = *(const float4*)(xr + k + 4);
            a0 += xA.x * w0; a1 += xA.y * w1; a2 += xA.z * w2; a3 += xA.w * w3;
            a0 += xB.x * w4; a1 += xB.y * w5; a2 += xB.z * w6; a3 += xB.w * w7;
        }
        float a = (a0 + a1) + (a2 + a3) + bp[p];
        // fast tanh: 1 - 2/(e^{2a}+1); inf-safe at both extremes
        float e  = __expf(2.0f * a);
        float ph = (1.0f - __fdividef(2.0f, e + 1.0f)) * PIF;
        const int row = row0 + rr;
        const int idx = row * P_ + p;
        phases_out[idx] = ph;
        float s, c;
        __sincosf(ph, &s, &c);
        if (phasorMode == 0) {
            ((float2*)phasor_out)[idx] = make_float2(c, s);
        } else if (phasorMode == 1) {
            phasor_out[idx] = c;
        }
        // ---- phasorT via LDS transpose (coalesced 32/64-B runs per p) ----
        if (hasPT) {
            const int bq    = row0 >> 10;        // block never crosses b
            const int row0l = row0 & (L_ - 1);
            if (mode == 1) {
                float* ct = xs + 2048;           // [32][9] padded, 288 fl
                ct[p * 9 + rr] = c;
                __syncthreads();
                if (tid < 32) {
                    const float* sp = ct + tid * 9;
                    float4 A  = { sp[0], sp[1], sp[2], sp[3] };
                    float4 Bv = { sp[4], sp[5], sp[6], sp[7] };
                    float4* dst = (float4*)(phasorT +
                        ((size_t)(bq * P_ + tid)) * L_ + row0l);
                    dst[0] = A; dst[1] = Bv;
                }
            } else {
                float2* ct2 = (float2*)(xs + 2048);  // [32][9] f2, 576 fl
                ct2[p * 9 + rr] = make_float2(c, s);
                __syncthreads();
                if (tid < 32) {
                    const float2* sp = ct2 + tid * 9;
                    float4* dst = (float4*)((float2*)phasorT +
                        ((size_t)(bq * P_ + tid)) * L_ + row0l);
                    dst[0] = make_float4(sp[0].x, sp[0].y, sp[1].x, sp[1].y);
                    dst[1] = make_float4(sp[2].x, sp[2].y, sp[3].x, sp[3].y);
                    dst[2] = make_float4(sp[4].x, sp[4].y, sp[5].x, sp[5].y);
                    dst[3] = make_float4(sp[6].x, sp[6].y, sp[7].x, sp[7].y);
                }
            }
        }
    }
}

// ---------------------------------------------------------------------------
// Fused partial+scan, block-INTERNAL prefix (round-7, unchanged — near write
// roofline). Grid (b, p, d8): 512 blocks x 256 threads; thread = (slot, col).
//  stage:  all 1024 phasors for (b,p) into LDS (coalesced float4)
//  phase1: thread computes chunk `slot`'s partial (uniform 64 iters, L2-hot
//          values loads) -> LDS part[16][16]; barrier
//  prefix: carry = sum part[cc<slot][col]  (<=15 LDS reads, block-local!)
//  phase2: 64-step running scan + NT store
// No cross-block sync, no S global round-trip, uniform work.
// ---------------------------------------------------------------------------
__global__ __launch_bounds__(256) void k_pscan(
    const float* __restrict__ values, const float* __restrict__ phases,
    const float* __restrict__ phasorT, float* __restrict__ mem,
    int mode, int hasPT)
{
    const int blk  = blockIdx.x;                 // b*P_*8 + p*8 + d8
    const int d8   = blk & 7;
    const int p    = (blk >> 3) & (P_ - 1);
    const int b    = blk >> 8;
    const int tid  = threadIdx.x;                // 0..255
    const int col  = tid & 15;
    const int slot = tid >> 4;                   // chunk index 0..15
    const int bp   = b * P_ + p;
    const int l0   = slot * CL_;

    __shared__ float sm[3072];                   // 12 KB max (mode 0)
    float*  pcs   = sm;                          // mode1: [1024] cos
    float2* pcs2  = (float2*)sm;                 // mode0: [1024] (cos,sin)
    float2* part2 = (float2*)(sm + 1024);        // mode1 partials [16][16]
    float4* part4 = (float4*)(sm + 2048);        // mode0 partials [16][16]

    if (hasPT) {
        if (mode == 1) {
            ((float4*)pcs)[tid] =
                ((const float4*)(phasorT + (size_t)bp * L_))[tid];   // 1024 fl
        } else {
            const float4* src =
                (const float4*)((const float2*)phasorT + (size_t)bp * L_);
            ((float4*)pcs2)[tid]       = src[tid];
            ((float4*)pcs2)[tid + 256] = src[tid + 256];
        }
    } else {
        for (int l = tid; l < L_; l += 256) {
            float ph = phases[(b * L_ + l) * P_ + p];
            if (mode == 1) pcs[l] = __cosf(ph);
            else           pcs2[l] = make_float2(__cosf(ph), __sinf(ph));
        }
    }
    __syncthreads();

    const float2* vbase =
        (const float2*)values + (size_t)(b * L_) * (D_/2) + d8 * 16 + col;

    if (mode == 1) {
        // ---- phase 1: chunk partial (independent iters, good ILP) ----
        float sx = 0.f, sy = 0.f;
        #pragma unroll 8
        for (int i = 0; i < CL_; ++i) {
            float  pc = pcs[l0 + i];             // bcast per 16-lane group
            float2 v  = vbase[(size_t)(l0 + i) * (D_/2)];
            sx += pc * v.x;
            sy += pc * v.y;
        }
        part2[slot * 16 + col] = make_float2(sx, sy);
        __syncthreads();

        // ---- block-local prefix: <=15 LDS reads ----
        float cx = 0.f, cz = 0.f;
        for (int cc = 0; cc < slot; ++cc) {
            float2 s = part2[cc * 16 + col];
            cx += s.x; cz += s.y;
        }

        // ---- phase 2: running scan + NT store ----
        nvf2* dst = (nvf2*)mem +
            ((size_t)(b * L_ + l0) * P_ + p) * (D_/2) + d8 * 16 + col;
        const size_t st = (size_t)P_ * (D_/2);   // l-row stride in float2
        #pragma unroll 8
        for (int i = 0; i < CL_; ++i) {
            float  pc = pcs[l0 + i];
            float2 v  = vbase[(size_t)(l0 + i) * (D_/2)];  // L2-hot (phase 1)
            cx += pc * v.x;
            cz += pc * v.y;
            nvf2 o = { cx, cz };
            __builtin_nontemporal_store(o, dst + (size_t)i * st);
        }
    } else {
        float4 a = make_float4(0.f, 0.f, 0.f, 0.f);
        #pragma unroll 8
        for (int i = 0; i < CL_; ++i) {
            float2 q = pcs2[l0 + i];
            float2 v = vbase[(size_t)(l0 + i) * (D_/2)];
            a.x += q.x * v.x; a.y += q.y * v.x;
            a.z += q.x * v.y; a.w += q.y * v.y;
        }
        part4[slot * 16 + col] = a;
        __syncthreads();

        float4 carry = make_float4(0.f, 0.f, 0.f, 0.f);
        for (int cc = 0; cc < slot; ++cc) {
            float4 s = part4[cc * 16 + col];
            carry.x += s.x; carry.y += s.y; carry.z += s.z; carry.w += s.w;
        }

        nvf4* dst = (nvf4*)mem +
            ((size_t)(b * L_ + l0) * P_ + p) * (D_/2) + d8 * 16 + col;
        const size_t st = (size_t)P_ * (D_/2);   // l-row stride in float4
        #pragma unroll 8
        for (int i = 0; i < CL_; ++i) {
            float2 q = pcs2[l0 + i];
            float2 v = vbase[(size_t)(l0 + i) * (D_/2)];
            carry.x += q.x * v.x; carry.y += q.y * v.x;
            carry.z += q.x * v.y; carry.w += q.y * v.y;
            nvf4 o = { carry.x, carry.y, carry.z, carry.w };
            __builtin_nontemporal_store(o, dst + (size_t)i * st);
        }
    }
}

// ---------------------------------------------------------------------------
// Path B parachute (small ws): carry recomputed from values/phases via L2.
// ---------------------------------------------------------------------------
__global__ __launch_bounds__(128) void k_scan_rc(
    const float* __restrict__ values, const float* __restrict__ phases,
    float* __restrict__ mem, int mode)
{
    const int blk = blockIdx.x;
    const int c = blk & (C_ - 1);
    const int p = (blk >> 4) & (P_ - 1);
    const int b = blk >> 9;
    const int tid = threadIdx.x;
    const int l0 = c * CL_;

    const float2* vb = (const float2*)(values + (size_t)b * L_ * D_);
    float4 carry = make_float4(0.f, 0.f, 0.f, 0.f);
    for (int l = 0; l < l0; ++l) {
        float ph = phases[(b * L_ + l) * P_ + p];
        float s = __sinf(ph), cs = __cosf(ph);
        float2 v = vb[l * (D_/2) + tid];
        carry.x += cs * v.x; carry.y += s * v.x;
        carry.z += cs * v.y; carry.w += s * v.y;
    }
    for (int i = 0; i < CL_; ++i) {
        const int l = l0 + i;
        float ph = phases[(b * L_ + l) * P_ + p];
        float s = __sinf(ph), cs = __cosf(ph);
        float2 v = vb[l * (D_/2) + tid];
        carry.x += cs * v.x; carry.y += s * v.x;
        carry.z += cs * v.y; carry.w += s * v.y;
        const size_t rowIdx = (size_t)(b * L_ + l) * P_ + p;
        if (mode == 0) ((float4*)mem)[rowIdx * (D_/2) + tid] = carry;
        else ((float2*)mem)[rowIdx * (D_/2) + tid] = make_float2(carry.x, carry.z);
    }
}

extern "C" void kernel_launch(void* const* d_in, const int* in_sizes, int n_in,
                              void* d_out, int out_size, void* d_ws, size_t ws_size,
                              hipStream_t stream) {
    const float* x  = (const float*)d_in[0];
    const float* Wp = (const float*)d_in[1];
    const float* bp = (const float*)d_in[2];
    const float* Wv = (const float*)d_in[3];
    const float* bv = (const float*)d_in[4];
    float* out = (float*)d_out;

    const size_t nMemF = (size_t)2 * B_ * L_ * P_ * D_;  // 33554432 (interleaved)
    const size_t nMemR = (size_t)B_ * L_ * P_ * D_;      // 16777216 (real only)
    const size_t nPh   = (size_t)B_ * L_ * P_;           // 65536

    // Output layout mode by out_size. Round-2/3 counter evidence: scan
    // WRITE_SIZE = 64 MiB = nMemR*4B => harness runs mode 1.
    int mode; size_t memFloats;
    if ((size_t)out_size >= nMemF + 3 * nPh) { mode = 0; memFloats = nMemF; }
    else                                     { mode = 1; memFloats = nMemR; }
    const bool memFits      = (size_t)out_size >= memFloats;
    const bool phasesInOut  = (size_t)out_size >= memFloats + nPh;
    const bool phasorsInOut =
        (size_t)out_size >= memFloats + nPh + (mode == 0 ? 2 * nPh : nPh);

    // ws layout: values | phasesWs | S(hole, legacy offset) | phasorT
    const size_t valB = (size_t)B_ * L_ * D_ * sizeof(float);                // 2 MB
    const size_t phB  = nPh * sizeof(float);                                 // 256 KB
    const size_t sB   = (size_t)B_ * P_ * C_ * (D_/2) * sizeof(float4);      // 2 MB hole
    const size_t ptB  = nPh * (mode == 0 ? sizeof(float2) : sizeof(float));  // 512/256 KB
    float* values   = (float*)d_ws;
    float* phasesWs = (float*)((char*)d_ws + valB);
    float* phasorT  = (float*)((char*)d_ws + valB + phB + sB);

    float* phasesPtr = phasesInOut ? (out + memFloats)
                     : (ws_size >= valB + phB ? phasesWs : nullptr);
    if (phasesPtr == nullptr) return;            // unreachable (ws verified big enough)

    float* phasorPtr = phasorsInOut ? (out + memFloats + nPh) : nullptr;
    const int phasorMode = phasorsInOut ? mode : 2;

    const bool pathA = ws_size >= valB + phB;                // values+phases fit
    const int  hasPT = (ws_size >= valB + phB + sB + ptB) ? 1 : 0;

    k_proj3<<<NROW / 8 + NROW / 8, 256, 0, stream>>>(
        x, Wp, bp, Wv, bv, values, phasesPtr, phasorPtr, phasorT,
        phasorMode, mode, hasPT);
    if (!memFits) return;

    if (pathA) {
        k_pscan<<<B_ * P_ * 8, 256, 0, stream>>>(values, phasesPtr, phasorT,
                                                 out, mode, hasPT);
    } else {
        k_scan_rc<<<B_ * P_ * C_, 128, 0, stream>>>(values, phasesPtr, out, mode);
    }
}

// Round 9
// 99.338 us; speedup vs baseline: 1.0870x; 1.0047x over previous
//
#include <hip/hip_runtime.h>
#include <math.h>

// Problem constants (from reference): B=2, L=1024, D=256, P=32
#define B_ 2
#define L_ 1024
#define D_ 256
#define P_ 32
#define NROW (B_*L_)          // 2048 flattened (b,l) rows
#define C_ 16                 // L chunks for the scan
#define CL_ (L_/C_)           // 64 positions per chunk
#define PCP 68                // padded pcs row stride: 68%4==0 (16B-aligned
                              // float4 staging), 68%32==4 -> the 4 slots of a
                              // wave land on distinct LDS banks (was 4-way)
#define PIF 3.14159265358979323846f

// Native clang vector types — required by __builtin_nontemporal_store
typedef float nvf4 __attribute__((ext_vector_type(4)));
typedef float nvf2 __attribute__((ext_vector_type(2)));

// ---------------------------------------------------------------------------
// Budget model (rounds 5-8 calibrated): ~69 us fixed harness fills per iter
// + proj ~7 (floor ~4) + k_pscan ~14.5 (floor 11.3 = 64 MiB NT @ 5.9 TB/s)
// + ~9 us launch gaps. Round-9: k_pscan keeps the chunk's 64 values in
// registers across the barrier (kills 64 MB phase-2 L2 re-reads) + padded
// pcs layout (kills the 4-way same-bank conflict on the slot-strided reads).
// Round-2 lesson: NO agent-scope atomics (per-XCD L2 invalidation storm).
// Round-4 lesson: keep per-block work UNIFORM (no triangular tails).
// Rule #20: vr[] only with fully-unrolled, compile-time-constant indexing.
// ---------------------------------------------------------------------------

// ---------------------------------------------------------------------------
// Projection kernel, 512 blocks x 256 threads (round-8 structure, unchanged).
//  blocks [0, 256): values GEMM, 8 rows/block, 4-way K-split, Wv read once
//    per block (64 MB L2 total); 32 KB LDS reduction.
//  blocks [256, 512): phase GEMM, 8 rows x 32 p; fast tanh + __sincosf;
//    phases/phasors -> out; transposed phasor copy via LDS transpose:
//      mode 1: phasorT is float  cos-only  [bp*L + l]   (256 KB)
//      mode 0: phasorT is float2 (cos,sin) [bp*L + l]   (512 KB)
// phasorMode: 0 = float2 (cos,sin), 1 = cos only, 2 = skip. hasPT: write pT.
// ---------------------------------------------------------------------------
__global__ __launch_bounds__(256) void k_proj3(
    const float* __restrict__ x, const float* __restrict__ Wp,
    const float* __restrict__ bp, const float* __restrict__ Wv,
    const float* __restrict__ bv, float* __restrict__ values,
    float* __restrict__ phases_out, float* __restrict__ phasor_out,
    float* __restrict__ phasorT, int phasorMode, int mode, int hasPT)
{
    __shared__ float smem[10240];                // 40 KB carved below
    const int tid = threadIdx.x;

    if (blockIdx.x < NROW / 8) {
        // ---- values: rows [row0, row0+8), K-split ----
        const int row0 = blockIdx.x * 8;
        float*  xsv = smem;                      // 2048 floats (8 KB)
        float4* red = (float4*)(smem + 2048);    // 2048 float4 (32 KB)

        const float4* xg4 = (const float4*)(x + (size_t)row0 * D_);
        ((float4*)xsv)[tid]       = xg4[tid];
        ((float4*)xsv)[tid + 256] = xg4[tid + 256];
        __syncthreads();

        const int q  = tid >> 6;                 // k-quarter, wave-uniform
        const int c4 = tid & 63;                 // float4 column group
        const float4* Wv4 = (const float4*)Wv;
        float4 acc[8];
        #pragma unroll
        for (int r = 0; r < 8; ++r) acc[r] = make_float4(0.f, 0.f, 0.f, 0.f);

        const int k0 = q * 64;
        for (int kk = 0; kk < 64; kk += 4) {
            const int k = k0 + kk;
            // 4 independent 16B Wv loads in flight (L2-resident per XCD)
            float4 w0 = Wv4[(k + 0) * 64 + c4]; // coalesced 1KB/wave
            float4 w1 = Wv4[(k + 1) * 64 + c4];
            float4 w2 = Wv4[(k + 2) * 64 + c4];
            float4 w3 = Wv4[(k + 3) * 64 + c4];
            #pragma unroll
            for (int r = 0; r < 8; ++r) {
                float4 xv = *(const float4*)(xsv + r * D_ + k);  // b128 bcast
                acc[r].x += xv.x*w0.x + xv.y*w1.x + xv.z*w2.x + xv.w*w3.x;
                acc[r].y += xv.x*w0.y + xv.y*w1.y + xv.z*w2.y + xv.w*w3.y;
                acc[r].z += xv.x*w0.z + xv.y*w1.z + xv.z*w2.z + xv.w*w3.z;
                acc[r].w += xv.x*w0.w + xv.y*w1.w + xv.z*w2.w + xv.w*w3.w;
            }
        }
        #pragma unroll
        for (int r = 0; r < 8; ++r) red[(r * 4 + q) * 64 + c4] = acc[r];
        __syncthreads();

        // 512 outputs (8 rows x 64 c4); 256 threads finalize 2 rows each
        const int cb = tid & 63;
        const float4 b4 = ((const float4*)bv)[cb];
        #pragma unroll
        for (int h = 0; h < 2; ++h) {
            const int r = (tid >> 6) + h * 4;    // rows 0..3 then 4..7
            float4 s0 = red[(r * 4 + 0) * 64 + cb];
            float4 s1 = red[(r * 4 + 1) * 64 + cb];
            float4 s2 = red[(r * 4 + 2) * 64 + cb];
            float4 s3 = red[(r * 4 + 3) * 64 + cb];
            float4 o;
            o.x = s0.x + s1.x + s2.x + s3.x + b4.x;
            o.y = s0.y + s1.y + s2.y + s3.y + b4.y;
            o.z = s0.z + s1.z + s2.z + s3.z + b4.z;
            o.w = s0.w + s1.w + s2.w + s3.w + b4.w;
            ((float4*)values)[(size_t)(row0 + r) * 64 + cb] = o;
        }
    } else {
        // ---- phases/phasors: rows [row0, row0+8) ----
        const int row0 = (blockIdx.x - NROW / 8) * 8;
        float* xs = smem;                        // 2048 floats (8 KB)
        const float4* xg4 = (const float4*)(x + (size_t)row0 * D_);
        ((float4*)xs)[tid]       = xg4[tid];
        ((float4*)xs)[tid + 256] = xg4[tid + 256];
        __syncthreads();

        const int p  = tid & (P_ - 1);
        const int rr = tid >> 5;                 // 0..7
        const float* xr = xs + rr * D_;
        float a0 = 0.f, a1 = 0.f, a2 = 0.f, a3 = 0.f;
        for (int k = 0; k < D_; k += 8) {
            float w0 = Wp[(k + 0) * P_ + p];
            float w1 = Wp[(k + 1) * P_ + p];
            float w2 = Wp[(k + 2) * P_ + p];
            float w3 = Wp[(k + 3) * P_ + p];
            float w4 = Wp[(k + 4) * P_ + p];
            float w5 = Wp[(k + 5) * P_ + p];
            float w6 = Wp[(k + 6) * P_ + p];
            float w7 = Wp[(k + 7) * P_ + p];
            float4 xA = *(const float4*)(xr + k);
            float4 xB = *(const float4*)(xr + k + 4);
            a0 += xA.x * w0; a1 += xA.y * w1; a2 += xA.z * w2; a3 += xA.w * w3;
            a0 += xB.x * w4; a1 += xB.y * w5; a2 += xB.z * w6; a3 += xB.w * w7;
        }
        float a = (a0 + a1) + (a2 + a3) + bp[p];
        // fast tanh: 1 - 2/(e^{2a}+1); inf-safe at both extremes
        float e  = __expf(2.0f * a);
        float ph = (1.0f - __fdividef(2.0f, e + 1.0f)) * PIF;
        const int row = row0 + rr;
        const int idx = row * P_ + p;
        phases_out[idx] = ph;
        float s, c;
        __sincosf(ph, &s, &c);
        if (phasorMode == 0) {
            ((float2*)phasor_out)[idx] = make_float2(c, s);
        } else if (phasorMode == 1) {
            phasor_out[idx] = c;
        }
        // ---- phasorT via LDS transpose (coalesced 32/64-B runs per p) ----
        if (hasPT) {
            const int bq    = row0 >> 10;        // block never crosses b
            const int row0l = row0 & (L_ - 1);
            if (mode == 1) {
                float* ct = xs + 2048;           // [32][9] padded, 288 fl
                ct[p * 9 + rr] = c;
                __syncthreads();
                if (tid < 32) {
                    const float* sp = ct + tid * 9;
                    float4 A  = { sp[0], sp[1], sp[2], sp[3] };
                    float4 Bv = { sp[4], sp[5], sp[6], sp[7] };
                    float4* dst = (float4*)(phasorT +
                        ((size_t)(bq * P_ + tid)) * L_ + row0l);
                    dst[0] = A; dst[1] = Bv;
                }
            } else {
                float2* ct2 = (float2*)(xs + 2048);  // [32][9] f2, 576 fl
                ct2[p * 9 + rr] = make_float2(c, s);
                __syncthreads();
                if (tid < 32) {
                    const float2* sp = ct2 + tid * 9;
                    float4* dst = (float4*)((float2*)phasorT +
                        ((size_t)(bq * P_ + tid)) * L_ + row0l);
                    dst[0] = make_float4(sp[0].x, sp[0].y, sp[1].x, sp[1].y);
                    dst[1] = make_float4(sp[2].x, sp[2].y, sp[3].x, sp[3].y);
                    dst[2] = make_float4(sp[4].x, sp[4].y, sp[5].x, sp[5].y);
                    dst[3] = make_float4(sp[6].x, sp[6].y, sp[7].x, sp[7].y);
                }
            }
        }
    }
}

// ---------------------------------------------------------------------------
// Fused partial+scan, block-internal prefix (round-9: values-in-registers).
// Grid (b, p, d8): 512 blocks x 256 threads; thread = (slot, col).
//  stage:  all 1024 phasors for (b,p) into PADDED LDS ([16][PCP] — the 4
//          slots of a wave now hit distinct banks; was 4-way same-bank)
//  phase1: load the chunk's 64 values into vr[64] REGISTERS (fully unrolled,
//          static indices — rule #20) while accumulating the chunk partial
//          -> LDS part[16][16]; barrier
//  prefix: carry = sum part[cc<slot][col]  (<=15 LDS reads, block-local)
//  phase2: pure FMA + NT store from vr — ZERO reloads (was 64 MB L2 re-read)
// No cross-block sync, no S round-trip, uniform work.
// ---------------------------------------------------------------------------
__global__ __launch_bounds__(256) void k_pscan(
    const float* __restrict__ values, const float* __restrict__ phases,
    const float* __restrict__ phasorT, float* __restrict__ mem,
    int mode, int hasPT)
{
    const int blk  = blockIdx.x;                 // b*P_*8 + p*8 + d8
    const int d8   = blk & 7;
    const int p    = (blk >> 3) & (P_ - 1);
    const int b    = blk >> 8;
    const int tid  = threadIdx.x;                // 0..255
    const int col  = tid & 15;
    const int slot = tid >> 4;                   // chunk index 0..15
    const int bp   = b * P_ + p;
    const int l0   = slot * CL_;

    __shared__ float sm[3200];                   // 12.8 KB max (mode 0)
    float*  pcsw  = sm;                          // mode1: [16][PCP] cos
    float2* pcs2w = (float2*)sm;                 // mode0: [16][PCP] (cos,sin)
    float2* part2 = (float2*)(sm + 16 * PCP);        // mode1 partials [16][16]
    float4* part4 = (float4*)(sm + 16 * PCP * 2);    // mode0 partials [16][16]

    if (hasPT) {
        if (mode == 1) {
            // 1024 floats via 256 float4, scattered into padded rows.
            // float4 never crosses a 64-elem chunk boundary; PCP%4==0 keeps
            // 16-B alignment.
            const float4* src = (const float4*)(phasorT + (size_t)bp * L_);
            float4 w = src[tid];
            const int l = tid * 4, s = l >> 6, i = l & 63;
            *(float4*)(pcsw + s * PCP + i) = w;
        } else {
            const float4* src =
                (const float4*)((const float2*)phasorT + (size_t)bp * L_);
            #pragma unroll
            for (int k = 0; k < 2; ++k) {
                const int j = tid + k * 256;     // float4 = 2 f2 elements
                float4 w = src[j];
                const int l = j * 2, s = l >> 6, i = l & 63;
                *(float4*)((float*)pcs2w + (s * PCP + i) * 2) = w;
            }
        }
    } else {
        for (int l = tid; l < L_; l += 256) {
            float ph = phases[(b * L_ + l) * P_ + p];
            const int s = l >> 6, i = l & 63;
            if (mode == 1) pcsw[s * PCP + i] = __cosf(ph);
            else pcs2w[s * PCP + i] = make_float2(__cosf(ph), __sinf(ph));
        }
    }
    __syncthreads();

    const float2* vbase =
        (const float2*)values + (size_t)(b * L_) * (D_/2) + d8 * 16 + col;

    if (mode == 1) {
        const float* pch = pcsw + slot * PCP;
        float2 vr[64];                           // 128 VGPRs, static idx only
        // ---- phase 1: load chunk into regs + partial (dual accumulators) ----
        float sxA = 0.f, syA = 0.f, sxB = 0.f, syB = 0.f;
        #pragma unroll
        for (int i = 0; i < CL_; ++i) {
            float2 v = vbase[(size_t)(l0 + i) * (D_/2)];
            vr[i] = v;
            float pc = pch[i];                   // conflict-free (PCP pad)
            if (i & 1) { sxB += pc * v.x; syB += pc * v.y; }
            else       { sxA += pc * v.x; syA += pc * v.y; }
        }
        part2[slot * 16 + col] = make_float2(sxA + sxB, syA + syB);
        __syncthreads();

        // ---- block-local prefix: <=15 LDS reads ----
        float cx = 0.f, cz = 0.f;
        for (int cc = 0; cc < slot; ++cc) {
            float2 s = part2[cc * 16 + col];
            cx += s.x; cz += s.y;
        }

        // ---- phase 2: pure FMA + NT store from registers ----
        nvf2* dst = (nvf2*)mem +
            ((size_t)(b * L_ + l0) * P_ + p) * (D_/2) + d8 * 16 + col;
        const size_t st = (size_t)P_ * (D_/2);   // l-row stride in float2
        #pragma unroll
        for (int i = 0; i < CL_; ++i) {
            float pc = pch[i];
            cx += pc * vr[i].x;
            cz += pc * vr[i].y;
            nvf2 o = { cx, cz };
            __builtin_nontemporal_store(o, dst + (size_t)i * st);
        }
    } else {
        const float2* pch = pcs2w + slot * PCP;
        float2 vr[64];
        float4 a = make_float4(0.f, 0.f, 0.f, 0.f);
        #pragma unroll
        for (int i = 0; i < CL_; ++i) {
            float2 v = vbase[(size_t)(l0 + i) * (D_/2)];
            vr[i] = v;
            float2 q = pch[i];
            a.x += q.x * v.x; a.y += q.y * v.x;
            a.z += q.x * v.y; a.w += q.y * v.y;
        }
        part4[slot * 16 + col] = a;
        __syncthreads();

        float4 carry = make_float4(0.f, 0.f, 0.f, 0.f);
        for (int cc = 0; cc < slot; ++cc) {
            float4 s = part4[cc * 16 + col];
            carry.x += s.x; carry.y += s.y; carry.z += s.z; carry.w += s.w;
        }

        nvf4* dst = (nvf4*)mem +
            ((size_t)(b * L_ + l0) * P_ + p) * (D_/2) + d8 * 16 + col;
        const size_t st = (size_t)P_ * (D_/2);   // l-row stride in float4
        #pragma unroll
        for (int i = 0; i < CL_; ++i) {
            float2 q = pch[i];
            carry.x += q.x * vr[i].x; carry.y += q.y * vr[i].x;
            carry.z += q.x * vr[i].y; carry.w += q.y * vr[i].y;
            nvf4 o = { carry.x, carry.y, carry.z, carry.w };
            __builtin_nontemporal_store(o, dst + (size_t)i * st);
        }
    }
}

// ---------------------------------------------------------------------------
// Path B parachute (small ws): carry recomputed from values/phases via L2.
// ---------------------------------------------------------------------------
__global__ __launch_bounds__(128) void k_scan_rc(
    const float* __restrict__ values, const float* __restrict__ phases,
    float* __restrict__ mem, int mode)
{
    const int blk = blockIdx.x;
    const int c = blk & (C_ - 1);
    const int p = (blk >> 4) & (P_ - 1);
    const int b = blk >> 9;
    const int tid = threadIdx.x;
    const int l0 = c * CL_;

    const float2* vb = (const float2*)(values + (size_t)b * L_ * D_);
    float4 carry = make_float4(0.f, 0.f, 0.f, 0.f);
    for (int l = 0; l < l0; ++l) {
        float ph = phases[(b * L_ + l) * P_ + p];
        float s = __sinf(ph), cs = __cosf(ph);
        float2 v = vb[l * (D_/2) + tid];
        carry.x += cs * v.x; carry.y += s * v.x;
        carry.z += cs * v.y; carry.w += s * v.y;
    }
    for (int i = 0; i < CL_; ++i) {
        const int l = l0 + i;
        float ph = phases[(b * L_ + l) * P_ + p];
        float s = __sinf(ph), cs = __cosf(ph);
        float2 v = vb[l * (D_/2) + tid];
        carry.x += cs * v.x; carry.y += s * v.x;
        carry.z += cs * v.y; carry.w += s * v.y;
        const size_t rowIdx = (size_t)(b * L_ + l) * P_ + p;
        if (mode == 0) ((float4*)mem)[rowIdx * (D_/2) + tid] = carry;
        else ((float2*)mem)[rowIdx * (D_/2) + tid] = make_float2(carry.x, carry.z);
    }
}

extern "C" void kernel_launch(void* const* d_in, const int* in_sizes, int n_in,
                              void* d_out, int out_size, void* d_ws, size_t ws_size,
                              hipStream_t stream) {
    const float* x  = (const float*)d_in[0];
    const float* Wp = (const float*)d_in[1];
    const float* bp = (const float*)d_in[2];
    const float* Wv = (const float*)d_in[3];
    const float* bv = (const float*)d_in[4];
    float* out = (float*)d_out;

    const size_t nMemF = (size_t)2 * B_ * L_ * P_ * D_;  // 33554432 (interleaved)
    const size_t nMemR = (size_t)B_ * L_ * P_ * D_;      // 16777216 (real only)
    const size_t nPh   = (size_t)B_ * L_ * P_;           // 65536

    // Output layout mode by out_size. Round-2/3 counter evidence: scan
    // WRITE_SIZE = 64 MiB = nMemR*4B => harness runs mode 1.
    int mode; size_t memFloats;
    if ((size_t)out_size >= nMemF + 3 * nPh) { mode = 0; memFloats = nMemF; }
    else                                     { mode = 1; memFloats = nMemR; }
    const bool memFits      = (size_t)out_size >= memFloats;
    const bool phasesInOut  = (size_t)out_size >= memFloats + nPh;
    const bool phasorsInOut =
        (size_t)out_size >= memFloats + nPh + (mode == 0 ? 2 * nPh : nPh);

    // ws layout: values | phasesWs | S(hole, legacy offset) | phasorT
    const size_t valB = (size_t)B_ * L_ * D_ * sizeof(float);                // 2 MB
    const size_t phB  = nPh * sizeof(float);                                 // 256 KB
    const size_t sB   = (size_t)B_ * P_ * C_ * (D_/2) * sizeof(float4);      // 2 MB hole
    const size_t ptB  = nPh * (mode == 0 ? sizeof(float2) : sizeof(float));  // 512/256 KB
    float* values   = (float*)d_ws;
    float* phasesWs = (float*)((char*)d_ws + valB);
    float* phasorT  = (float*)((char*)d_ws + valB + phB + sB);

    float* phasesPtr = phasesInOut ? (out + memFloats)
                     : (ws_size >= valB + phB ? phasesWs : nullptr);
    if (phasesPtr == nullptr) return;            // unreachable (ws verified big enough)

    float* phasorPtr = phasorsInOut ? (out + memFloats + nPh) : nullptr;
    const int phasorMode = phasorsInOut ? mode : 2;

    const bool pathA = ws_size >= valB + phB;                // values+phases fit
    const int  hasPT = (ws_size >= valB + phB + sB + ptB) ? 1 : 0;

    k_proj3<<<NROW / 8 + NROW / 8, 256, 0, stream>>>(
        x, Wp, bp, Wv, bv, values, phasesPtr, phasorPtr, phasorT,
        phasorMode, mode, hasPT);
    if (!memFits) return;

    if (pathA) {
        k_pscan<<<B_ * P_ * 8, 256, 0, stream>>>(values, phasesPtr, phasorT,
                                                 out, mode, hasPT);
    } else {
        k_scan_rc<<<B_ * P_ * C_, 128, 0, stream>>>(values, phasesPtr, out, mode);
    }
}